// Round 6
// baseline (270.205 us; speedup 1.0000x reference)
//
#include <hip/hip_runtime.h>
#include <hip/hip_bf16.h>
#include <stdint.h>

#define N_REP 8
#define BATCH 32
#define NIN   128
#define NOUT  128
#define EDIM  1024
#define MDIM  130
#define SROW  36    // LDS row stride (dwords) per mp-row: 32 data + 4 pad
#define SLICE (16 * SROW)   // one 32m x 32e packed slice = 576 dwords = 2304 B

typedef __attribute__((ext_vector_type(8))) short short8;
typedef __attribute__((ext_vector_type(4))) float f32x4;

__device__ __forceinline__ unsigned short f2bf(float f) {
    union { float f; uint32_t u; } v;
    v.f = f;
    uint32_t u = v.u;
    uint32_t r = u + 0x7fffu + ((u >> 16) & 1u);   // RNE
    return (unsigned short)(r >> 16);
}

__device__ __forceinline__ uint32_t pk2bf(float lo, float hi) {
    __hip_bfloat162 h = __float22bfloat162_rn(make_float2(lo, hi)); // .x -> low16
    uint32_t d;
    __builtin_memcpy(&d, &h, 4);
    return d;
}

// One wave per (n,o). m parallel across lanes: m = lane, lane+64, (lane<2: 128+lane).
// Emits S[n][o][m] = W*sign (bf16, K-minor) and bias[n][o] = sum Wneg(m<128) + Wpos(m=128).
__global__ __launch_bounds__(64)
void prep_kernel(const float* __restrict__ theta,
                 const float* __restrict__ noise,
                 unsigned short* __restrict__ Sg,
                 float* __restrict__ biasg) {
    const int n = blockIdx.x >> 7;
    const int o = blockIdx.x & 127;
    const int lane = threadIdx.x;

    const float* nb = noise + (size_t)n * MDIM * NOUT + o;
    auto tn_at = [&](int m) -> float {
        float t = theta[m * NOUT + o];
        t = fminf(fmaxf(t, -1.f), 1.f);
        if (fabsf(t) < 0.01f) t = 0.f;
        return t * fmaf(nb[m * NOUT], 0.2f, 0.9f);
    };

    const float t0 = tn_at(lane);
    const float t1 = tn_at(lane + 64);
    const float t2 = (lane < 2) ? tn_at(128 + lane) : 0.f;

    float s = fabsf(t0) + fabsf(t1) + fabsf(t2);
#pragma unroll
    for (int d = 1; d < 64; d <<= 1) s += __shfl_xor(s, d, 64);
    const float inv = 1.f / (s + 1e-10f);

    const float w0 = fabsf(t0) * inv, w1 = fabsf(t1) * inv;
    unsigned short* srow = Sg + ((size_t)n * NOUT + o) * NIN;
    srow[lane]      = f2bf(t0 >= 0.f ? w0 : -w0);
    srow[lane + 64] = f2bf(t1 >= 0.f ? w1 : -w1);

    float b = (t0 < 0.f ? w0 : 0.f) + (t1 < 0.f ? w1 : 0.f);
    if (lane == 0 && t2 >= 0.f) b += fabsf(t2) * inv;   // ones-column positive part
#pragma unroll
    for (int d = 1; d < 64; d <<= 1) b += __shfl_xor(b, d, 64);
    if (lane == 0) biasg[n * NOUT + o] = b;
}

// out[nb][o][e] = tanh-act( sum_m a[nb][m][e] * S[n][o][m] + bias[n][o] ).
// WAVE-PRIVATE STREAMER: each wave = independent [o=128][e=32] tile; a read
// exactly once device-wide. Per 32-m slice: 4 float4 loads (1 KB/wave-instr,
// fully coalesced) -> pack bf16 m-pairs -> wave-private LDS slice (written and
// read by the SAME wave: in-order DS pipe + lgkmcnt, NO __syncthreads anywhere,
// so no vmcnt(0) barrier drains). Software pipeline 1-deep: issue loads(t+1),
// compute(t), pack_write(t+1) [vmcnt wait covered by compute], issue(t+2).
// S-frag loads (L2-hot) interleave with MFMAs inside compute -> continuous
// vmem issue per wave; 12-16 waves/CU each with ~4KB in flight.
__global__ __launch_bounds__(256, 3)
void gemm_kernel(const float* __restrict__ a,
                 const unsigned short* __restrict__ Sg,
                 const float* __restrict__ biasg,
                 const float* __restrict__ eta,
                 float* __restrict__ out) {
    __shared__ uint32_t Alds[4][2][SLICE];          // 18432 B, wave-private slices
    const int bid  = blockIdx.x;
    const int nb   = bid >> 3;                      // n*B + b
    const int n    = nb >> 5;
    const int eb   = bid & 7;                       // 128-wide e-block
    const int tid  = threadIdx.x;
    const int lane = tid & 63;
    const int wv   = tid >> 6;
    const int r    = lane & 15;
    const int q    = lane >> 4;
    const int e0   = (eb << 7) + (wv << 5);         // wave's 32-wide e-base

    const int mp_l = lane >> 2;                     // 0..15: lane's mp-row
    const int ec   = (lane & 3) << 2;               // 0..12: lane's e-chunk
    const float* abase = a + (size_t)nb * (NIN * EDIM) + e0 + ec;
    uint32_t* L = &Alds[wv][0][0];

    float4 va[2], vb[2];                            // 1-deep staging regs (16 VGPR)
    auto issue = [&](int t) {                       // slice t: m = 32t..32t+31
        const float* gp = abase + (size_t)(2 * mp_l + (t << 5)) * EDIM;
#pragma unroll
        for (int i = 0; i < 2; ++i) {
            va[i] = *(const float4*)(gp + (i << 4));
            vb[i] = *(const float4*)(gp + EDIM + (i << 4));
        }
    };
    auto pack_write = [&](int buf) {
#pragma unroll
        for (int i = 0; i < 2; ++i) {
            uint4 d;
            d.x = pk2bf(va[i].x, vb[i].x);
            d.y = pk2bf(va[i].y, vb[i].y);
            d.z = pk2bf(va[i].z, vb[i].z);
            d.w = pk2bf(va[i].w, vb[i].w);
            *(uint4*)&L[buf * SLICE + mp_l * SROW + ec + (i << 4)] = d;
        }
    };

    // eta scalars forced into VGPRs: avoids two-SGPR VOP3 (constant-bus violation)
    float e0f = eta[0], e1f = eta[1], e2f = eta[2], e3f = eta[3];
    asm volatile("" : "+v"(e0f), "+v"(e1f), "+v"(e2f), "+v"(e3f));

    f32x4 acc[8][2];                                // [fo][fe]: o=128 x e=32
#pragma unroll
    for (int fo = 0; fo < 8; ++fo)
#pragma unroll
        for (int fe = 0; fe < 2; ++fe)
            acc[fo][fe] = (f32x4){0.f, 0.f, 0.f, 0.f};

    const unsigned short* sbase = Sg + ((size_t)(n * NOUT) << 7) + (q << 3);

    // prologue: slice 0 through the pipe, slice 1 in flight
    issue(0);
    pack_write(0);
    issue(1);

#pragma unroll
    for (int t = 0; t < 4; ++t) {
        const int buf = t & 1;
        // ---- compute slice t from wave-private LDS ----
        // frag read: 4 x ds_read_b32, banks (16q + 4jj + r): 2-way aliasing (free)
        short8 af[2];
#pragma unroll
        for (int fe = 0; fe < 2; ++fe) {
            uint32_t d[4];
#pragma unroll
            for (int jj = 0; jj < 4; ++jj)
                d[jj] = L[buf * SLICE + ((q << 2) + jj) * SROW + (fe << 4) + r];
            __builtin_memcpy(&af[fe], d, 16);
        }
        // S frags (L2-hot) interleaved with MFMAs: continuous vmem issue
#pragma unroll
        for (int fo2 = 0; fo2 < 4; ++fo2) {
            const short8 s0 = *(const short8*)(sbase + ((size_t)((fo2 << 5) + r) << 7) + (t << 5));
            const short8 s1 = *(const short8*)(sbase + ((size_t)((fo2 << 5) + 16 + r) << 7) + (t << 5));
#pragma unroll
            for (int fe = 0; fe < 2; ++fe) {
                acc[fo2 * 2][fe] = __builtin_amdgcn_mfma_f32_16x16x32_bf16(
                    af[fe], s0, acc[fo2 * 2][fe], 0, 0, 0);
                acc[fo2 * 2 + 1][fe] = __builtin_amdgcn_mfma_f32_16x16x32_bf16(
                    af[fe], s1, acc[fo2 * 2 + 1][fe], 0, 0, 0);
            }
        }
        // ---- pipeline maintenance ----
        if (t < 3) {
            pack_write(buf ^ 1);                    // waits slice t+1 (issued 1 iter ago)
            if (t < 2) issue(t + 2);
        }
    }

    // ---- epilogue: bias + printed tanh; lane owns 4 consecutive e -> float4 ----
    float* obase = out + (size_t)nb * (NOUT * EDIM) + e0;
#pragma unroll
    for (int fo = 0; fo < 8; ++fo) {
        const float bv = biasg[n * NOUT + (fo << 4) + r];
        float* orow = obase + (size_t)((fo << 4) + r) * EDIM;
#pragma unroll
        for (int fe = 0; fe < 2; ++fe) {
            f32x4 res;
#pragma unroll
            for (int i = 0; i < 4; ++i) {
                const float z = acc[fo][fe][i] + bv;
                const float y = (z - e2f) * e3f;
                const float ex = __expf(2.f * y);
                const float th = 1.f - 2.f * __builtin_amdgcn_rcpf(ex + 1.f);
                res[i] = fmaf(e1f, th, e0f);
            }
            *(f32x4*)(orow + (fe << 4) + (q << 2)) = res;
        }
    }
}

extern "C" void kernel_launch(void* const* d_in, const int* in_sizes, int n_in,
                              void* d_out, int out_size, void* d_ws, size_t ws_size,
                              hipStream_t stream) {
    const float* a     = (const float*)d_in[0];
    const float* theta = (const float*)d_in[1];
    const float* noise = (const float*)d_in[2];
    const float* eta   = (const float*)d_in[3];
    float* out = (float*)d_out;

    unsigned short* Sg = (unsigned short*)d_ws;      // 8*128*128 bf16 = 256 KiB
    float* biasg = (float*)((char*)d_ws + (size_t)N_REP * NOUT * NIN * sizeof(unsigned short));

    prep_kernel<<<N_REP * NOUT, 64, 0, stream>>>(theta, noise, Sg, biasg);
    gemm_kernel<<<N_REP * BATCH * 8, 256, 0, stream>>>(a, Sg, biasg, eta, out);
}

// Round 7
// 258.772 us; speedup vs baseline: 1.0442x; 1.0442x over previous
//
#include <hip/hip_runtime.h>
#include <hip/hip_bf16.h>
#include <stdint.h>

#define N_REP 8
#define BATCH 32
#define NIN   128
#define NOUT  128
#define EDIM  1024
#define MDIM  130
#define ETB   256   // e-extent per block
#define LROW  17    // LDS dwords per e-row: 16 mp-dwords + 1 pad (gcd(17,32)=1 -> spread reads)
#define NSL   4     // m-slices of 32

typedef __attribute__((ext_vector_type(8))) short short8;
typedef __attribute__((ext_vector_type(4))) float f32x4;

__device__ __forceinline__ unsigned short f2bf(float f) {
    union { float f; uint32_t u; } v;
    v.f = f;
    uint32_t u = v.u;
    uint32_t r = u + 0x7fffu + ((u >> 16) & 1u);   // RNE
    return (unsigned short)(r >> 16);
}

__device__ __forceinline__ uint32_t pk2bf(float lo, float hi) {
    __hip_bfloat162 h = __float22bfloat162_rn(make_float2(lo, hi)); // .x -> low16
    uint32_t d;
    __builtin_memcpy(&d, &h, 4);
    return d;
}

// One wave per (n,o). m parallel across lanes: m = lane, lane+64, (lane<2: 128+lane).
// Emits S[n][o][m] = W*sign (bf16, K-minor) and bias[n][o] = sum Wneg(m<128) + Wpos(m=128).
__global__ __launch_bounds__(64)
void prep_kernel(const float* __restrict__ theta,
                 const float* __restrict__ noise,
                 unsigned short* __restrict__ Sg,
                 float* __restrict__ biasg) {
    const int n = blockIdx.x >> 7;
    const int o = blockIdx.x & 127;
    const int lane = threadIdx.x;

    const float* nb = noise + (size_t)n * MDIM * NOUT + o;
    auto tn_at = [&](int m) -> float {
        float t = theta[m * NOUT + o];
        t = fminf(fmaxf(t, -1.f), 1.f);
        if (fabsf(t) < 0.01f) t = 0.f;
        return t * fmaf(nb[m * NOUT], 0.2f, 0.9f);
    };

    const float t0 = tn_at(lane);
    const float t1 = tn_at(lane + 64);
    const float t2 = (lane < 2) ? tn_at(128 + lane) : 0.f;

    float s = fabsf(t0) + fabsf(t1) + fabsf(t2);
#pragma unroll
    for (int d = 1; d < 64; d <<= 1) s += __shfl_xor(s, d, 64);
    const float inv = 1.f / (s + 1e-10f);

    const float w0 = fabsf(t0) * inv, w1 = fabsf(t1) * inv;
    unsigned short* srow = Sg + ((size_t)n * NOUT + o) * NIN;
    srow[lane]      = f2bf(t0 >= 0.f ? w0 : -w0);
    srow[lane + 64] = f2bf(t1 >= 0.f ? w1 : -w1);

    float b = (t0 < 0.f ? w0 : 0.f) + (t1 < 0.f ? w1 : 0.f);
    if (lane == 0 && t2 >= 0.f) b += fabsf(t2) * inv;   // ones-column positive part
#pragma unroll
    for (int d = 1; d < 64; d <<= 1) b += __shfl_xor(b, d, 64);
    if (lane == 0) biasg[n * NOUT + o] = b;
}

// out[nb][o][e] = tanh-act( sum_m a[nb][m][e] * S[n][o][m] + bias[n][o] ).
// CONTIGUOUS-SEGMENT STAGING: every a-load wave-instruction is ONE contiguous
// 1 KB span (64 lanes x 16B of a single [m]-row segment) -- the copy-kernel
// pattern that reaches ~6.3 TB/s. All six prior variants issued 16 scattered
// 64B segments at 4KB stride per instr (same channel subset -> ~2 TB/s cap
// invariant to occupancy/barriers/pipelining). Block = [o=128][e=256], 8 waves,
// double-buffered e-major LDS [e][mp] (pad 1: gcd(17,32)=1 spreads frag reads);
// per 32-m slice each wave loads 4 full row-segments. One sync per slice;
// in-flight loads are consumed by pack_write BEFORE the barrier (no drain loss).
__global__ __launch_bounds__(512, 4)
void gemm_kernel(const float* __restrict__ a,
                 const unsigned short* __restrict__ Sg,
                 const float* __restrict__ biasg,
                 const float* __restrict__ eta,
                 float* __restrict__ out) {
    __shared__ uint32_t Alds[2][ETB][LROW];          // 34816 B -> 2 blocks/CU (16 waves)
    const int bid  = blockIdx.x;
    const int nb   = bid >> 2;                       // n*B + b
    const int n    = nb >> 5;
    const int et   = bid & 3;                        // 256-wide e-chunk
    const int tid  = threadIdx.x;
    const int lane = tid & 63;
    const int wv   = tid >> 6;                       // 8 waves
    const int r    = lane & 15;
    const int q    = lane >> 4;

    // ---- staging geometry: wave wv loads rows {2wv, 2wv+1, 2wv+16, 2wv+17} of the
    // slice, each row-segment as ONE contiguous 1KB wave-instruction (lane = e/4)
    const int eL = lane << 2;                        // float idx 0..252 within ETB
    const float* gA = a + (size_t)nb * (NIN * EDIM) + et * ETB + eL;

    f32x4 va0, va1, vb0, vb1;                        // staging regs (16 VGPR)
    auto issue = [&](int s) {
        const float* gp = gA + (size_t)(s * 32 + (wv << 1)) * EDIM;
        va0 = *(const f32x4*)(gp);
        va1 = *(const f32x4*)(gp + EDIM);
        vb0 = *(const f32x4*)(gp + 16 * EDIM);
        vb1 = *(const f32x4*)(gp + 17 * EDIM);
    };
    auto pack_write = [&](int buf) {                 // e-major: Alds[e][mp]
#pragma unroll
        for (int j = 0; j < 4; ++j) {
            Alds[buf][eL + j][wv]     = pk2bf(va0[j], va1[j]);
            Alds[buf][eL + j][wv + 8] = pk2bf(vb0[j], vb1[j]);
        }
    };

    f32x4 acc[8][2];                                 // [fo][fe]: o=128 x e=32 per wave
#pragma unroll
    for (int fo = 0; fo < 8; ++fo)
#pragma unroll
        for (int fe = 0; fe < 2; ++fe)
            acc[fo][fe] = (f32x4){0.f, 0.f, 0.f, 0.f};

    const unsigned short* sbase = Sg + ((size_t)(n * NOUT) << 7) + (q << 3);

    issue(0);
    pack_write(0);
    __syncthreads();                                 // nothing else outstanding: cheap

#pragma unroll
    for (int t = 0; t < NSL; ++t) {
        const int buf = t & 1;
        if (t + 1 < NSL) issue(t + 1);               // in flight across compute(t)

        // a-fragments: 4 x ds_read_b32, addr/4 = 17e + 4q + jj, gcd(17,32)=1 -> ~2-way
        short8 af[2];
#pragma unroll
        for (int fe = 0; fe < 2; ++fe) {
            const int e = (wv << 5) + (fe << 4) + r;
            uint32_t d[4];
#pragma unroll
            for (int jj = 0; jj < 4; ++jj)
                d[jj] = Alds[buf][e][(q << 2) + jj];
            __builtin_memcpy(&af[fe], d, 16);
        }
        // S fragments (L2-hot) interleaved with MFMAs
#pragma unroll
        for (int fo2 = 0; fo2 < 4; ++fo2) {
            const short8 s0 = *(const short8*)(sbase + ((size_t)((fo2 << 5) + r) << 7) + (t << 5));
            const short8 s1 = *(const short8*)(sbase + ((size_t)((fo2 << 5) + 16 + r) << 7) + (t << 5));
#pragma unroll
            for (int fe = 0; fe < 2; ++fe) {
                acc[fo2 * 2][fe] = __builtin_amdgcn_mfma_f32_16x16x32_bf16(
                    af[fe], s0, acc[fo2 * 2][fe], 0, 0, 0);
                acc[fo2 * 2 + 1][fe] = __builtin_amdgcn_mfma_f32_16x16x32_bf16(
                    af[fe], s1, acc[fo2 * 2 + 1][fe], 0, 0, 0);
            }
        }

        if (t + 1 < NSL) {
            pack_write(buf ^ 1);                     // consumes issue(t+1) loads
            __syncthreads();                         // barrier drain costs nothing extra
        }
    }

    // ---- epilogue: bias + printed tanh; lane owns 4 consecutive e -> float4 ----
    float e0f = eta[0], e1f = eta[1], e2f = eta[2], e3f = eta[3];
    asm volatile("" : "+v"(e0f), "+v"(e1f), "+v"(e2f), "+v"(e3f));  // no 2-SGPR VOP3
    float* obase = out + (size_t)nb * (NOUT * EDIM) + et * ETB + (wv << 5);
#pragma unroll
    for (int fo = 0; fo < 8; ++fo) {
        const float bv = biasg[n * NOUT + (fo << 4) + r];
        float* orow = obase + (size_t)((fo << 4) + r) * EDIM;
#pragma unroll
        for (int fe = 0; fe < 2; ++fe) {
            f32x4 res;
#pragma unroll
            for (int i = 0; i < 4; ++i) {
                const float z = acc[fo][fe][i] + bv;
                const float y = (z - e2f) * e3f;
                const float ex = __expf(2.f * y);
                const float th = 1.f - 2.f * __builtin_amdgcn_rcpf(ex + 1.f);
                res[i] = fmaf(e1f, th, e0f);
            }
            *(f32x4*)(orow + (fe << 4) + (q << 2)) = res;
        }
    }
}

extern "C" void kernel_launch(void* const* d_in, const int* in_sizes, int n_in,
                              void* d_out, int out_size, void* d_ws, size_t ws_size,
                              hipStream_t stream) {
    const float* a     = (const float*)d_in[0];
    const float* theta = (const float*)d_in[1];
    const float* noise = (const float*)d_in[2];
    const float* eta   = (const float*)d_in[3];
    float* out = (float*)d_out;

    unsigned short* Sg = (unsigned short*)d_ws;      // 8*128*128 bf16 = 256 KiB
    float* biasg = (float*)((char*)d_ws + (size_t)N_REP * NOUT * NIN * sizeof(unsigned short));

    prep_kernel<<<N_REP * NOUT, 64, 0, stream>>>(theta, noise, Sg, biasg);
    gemm_kernel<<<N_REP * BATCH * (EDIM / ETB), 512, 0, stream>>>(a, Sg, biasg, eta, out);
}

// Round 8
// 254.615 us; speedup vs baseline: 1.0612x; 1.0163x over previous
//
#include <hip/hip_runtime.h>
#include <hip/hip_bf16.h>
#include <stdint.h>

#define N_REP 8
#define BATCH 32
#define NIN   128
#define NOUT  128
#define EDIM  1024
#define MDIM  130
#define ETILE 128
#define SE    130   // LDS row stride in dwords (mp rows); 130 => frag reads 2-way (free)

typedef __attribute__((ext_vector_type(8))) short short8;
typedef __attribute__((ext_vector_type(4))) float f32x4;

__device__ __forceinline__ unsigned short f2bf(float f) {
    union { float f; uint32_t u; } v;
    v.f = f;
    uint32_t u = v.u;
    uint32_t r = u + 0x7fffu + ((u >> 16) & 1u);   // RNE
    return (unsigned short)(r >> 16);
}

__device__ __forceinline__ uint32_t pk2bf(float lo, float hi) {
    __hip_bfloat162 h = __float22bfloat162_rn(make_float2(lo, hi)); // .x -> low16
    uint32_t d;
    __builtin_memcpy(&d, &h, 4);
    return d;
}

// One wave per (n,o). m parallel across lanes: m = lane, lane+64, (lane<2: 128+lane).
// Emits S[n][o][m] = W*sign (bf16, K-minor) and bias[n][o] = sum Wneg(m<128) + Wpos(m=128).
__global__ __launch_bounds__(64)
void prep_kernel(const float* __restrict__ theta,
                 const float* __restrict__ noise,
                 unsigned short* __restrict__ Sg,
                 float* __restrict__ biasg) {
    const int n = blockIdx.x >> 7;
    const int o = blockIdx.x & 127;
    const int lane = threadIdx.x;

    const float* nb = noise + (size_t)n * MDIM * NOUT + o;
    auto tn_at = [&](int m) -> float {
        float t = theta[m * NOUT + o];
        t = fminf(fmaxf(t, -1.f), 1.f);
        if (fabsf(t) < 0.01f) t = 0.f;
        return t * fmaf(nb[m * NOUT], 0.2f, 0.9f);
    };

    const float t0 = tn_at(lane);
    const float t1 = tn_at(lane + 64);
    const float t2 = (lane < 2) ? tn_at(128 + lane) : 0.f;

    float s = fabsf(t0) + fabsf(t1) + fabsf(t2);
#pragma unroll
    for (int d = 1; d < 64; d <<= 1) s += __shfl_xor(s, d, 64);
    const float inv = 1.f / (s + 1e-10f);

    const float w0 = fabsf(t0) * inv, w1 = fabsf(t1) * inv;
    unsigned short* srow = Sg + ((size_t)n * NOUT + o) * NIN;
    srow[lane]      = f2bf(t0 >= 0.f ? w0 : -w0);
    srow[lane + 64] = f2bf(t1 >= 0.f ? w1 : -w1);

    float b = (t0 < 0.f ? w0 : 0.f) + (t1 < 0.f ? w1 : 0.f);
    if (lane == 0 && t2 >= 0.f) b += fabsf(t2) * inv;   // ones-column positive part
#pragma unroll
    for (int d = 1; d < 64; d <<= 1) b += __shfl_xor(b, d, 64);
    if (lane == 0) biasg[n * NOUT + o] = b;
}

// D[o][e] = sum_m S[n][o][m] * a[n][b][m][e] via bf16 MFMA; + bias, printed tanh.
// LDS a-tile: bf16 packed m-pairs, Alds[mp*SE + e] = (bf16(2mp,e) | bf16(2mp+1,e)<<16).
// 32.5 KiB => 4 blocks/CU. Frag = 4 x ds_read_b32, no repacking.
// NOTE (session close): 7 structural variants (DMA, pipelined vmcnt, no-LDS direct,
// wave-private streamer, contiguous-segment staging) all cap at 2.0-2.3 TB/s HBM;
// this variant is the best-measured overall. Empirical cap, not kernel-structural.
__global__ __launch_bounds__(256, 4)
void gemm_kernel(const float* __restrict__ a,
                 const unsigned short* __restrict__ Sg,
                 const float* __restrict__ biasg,
                 const float* __restrict__ eta,
                 float* __restrict__ out) {
    __shared__ uint32_t Alds[64 * SE];               // 33280 B
    const int bid = blockIdx.x;
    const int et  = bid & 7;
    const int nb  = bid >> 3;                        // n*B + b
    const int n   = nb >> 5;
    const int tid = threadIdx.x;

    // ---- stage A tile: fp32 [m][e] -> bf16 m-pair-packed [mp][e] ----
    {
        const float* abase = a + (size_t)nb * (NIN * EDIM) + et * ETILE;
        const int e4  = (tid & 31) << 2;
        const int mp0 = tid >> 5;                    // 0..7
#pragma unroll
        for (int it = 0; it < 8; ++it) {
            const int mp = mp0 + (it << 3);
            const float4 va = *(const float4*)(abase + (size_t)(2 * mp) * EDIM + e4);
            const float4 vb = *(const float4*)(abase + (size_t)(2 * mp + 1) * EDIM + e4);
            uint2 d0, d1;
            d0.x = pk2bf(va.x, vb.x);
            d0.y = pk2bf(va.y, vb.y);
            d1.x = pk2bf(va.z, vb.z);
            d1.y = pk2bf(va.w, vb.w);
            *(uint2*)&Alds[mp * SE + e4]     = d0;
            *(uint2*)&Alds[mp * SE + e4 + 2] = d1;
        }
    }
    __syncthreads();

    const int lane = tid & 63;
    const int w = tid >> 6;                          // 2x2 waves over (o,e)
    const int r = lane & 15;
    const int q = lane >> 4;
    const int o_base = (w & 1) << 6;
    const int e_base = (w >> 1) << 6;

    f32x4 acc[4][4];
#pragma unroll
    for (int fo = 0; fo < 4; ++fo)
#pragma unroll
        for (int fe = 0; fe < 4; ++fe)
            acc[fo][fe] = (f32x4){0.f, 0.f, 0.f, 0.f};

#pragma unroll
    for (int ks = 0; ks < 4; ++ks) {
        // S fragments (A-operand): contiguous 16 B from global (L2-hot, 32 KiB/n)
        short8 sf[4];
#pragma unroll
        for (int fo = 0; fo < 4; ++fo) {
            const int o = o_base + (fo << 4) + r;
            sf[fo] = *(const short8*)(Sg + ((size_t)(n * NOUT + o) << 7) + (ks << 5) + (q << 3));
        }
        // a fragments (B-operand): 4 dwords each, dword = 2 consecutive-k bf16
        short8 af[4];
        const int mpb = (ks << 4) + (q << 2);
#pragma unroll
        for (int fe = 0; fe < 4; ++fe) {
            const int e = e_base + (fe << 4) + r;
            uint32_t d[4];
#pragma unroll
            for (int jj = 0; jj < 4; ++jj)
                d[jj] = Alds[(mpb + jj) * SE + e];
            __builtin_memcpy(&af[fe], d, 16);
        }
#pragma unroll
        for (int fo = 0; fo < 4; ++fo)
#pragma unroll
            for (int fe = 0; fe < 4; ++fe)
                acc[fo][fe] = __builtin_amdgcn_mfma_f32_16x16x32_bf16(
                    sf[fo], af[fe], acc[fo][fe], 0, 0, 0);
    }

    // ---- epilogue: bias + printed tanh, store out[n][b][o][e] ----
    const float e0 = eta[0], e1 = eta[1], e2 = eta[2], e3 = eta[3];
    float* obase = out + (size_t)nb * (NOUT * EDIM) + et * ETILE;
#pragma unroll
    for (int fo = 0; fo < 4; ++fo) {
        const int orow0 = o_base + (fo << 4) + (q << 2);       // C/D: row = q*4+i
        const float4 bias4 = *(const float4*)(biasg + n * NOUT + orow0);
        const float bv[4] = {bias4.x, bias4.y, bias4.z, bias4.w};
#pragma unroll
        for (int i = 0; i < 4; ++i) {
            float* orow = obase + (size_t)(orow0 + i) * EDIM;
#pragma unroll
            for (int fe = 0; fe < 4; ++fe) {
                const float z = acc[fo][fe][i] + bv[i];
                const float y = (z - e2) * e3;
                const float ex = __expf(2.f * y);
                const float th = 1.f - 2.f * __builtin_amdgcn_rcpf(ex + 1.f);
                orow[e_base + (fe << 4) + r] = fmaf(e1, th, e0);  // C/D: col = r
            }
        }
    }
}

extern "C" void kernel_launch(void* const* d_in, const int* in_sizes, int n_in,
                              void* d_out, int out_size, void* d_ws, size_t ws_size,
                              hipStream_t stream) {
    const float* a     = (const float*)d_in[0];
    const float* theta = (const float*)d_in[1];
    const float* noise = (const float*)d_in[2];
    const float* eta   = (const float*)d_in[3];
    float* out = (float*)d_out;

    unsigned short* Sg = (unsigned short*)d_ws;      // 8*128*128 bf16 = 256 KiB
    float* biasg = (float*)((char*)d_ws + (size_t)N_REP * NOUT * NIN * sizeof(unsigned short));

    prep_kernel<<<N_REP * NOUT, 64, 0, stream>>>(theta, noise, Sg, biasg);
    gemm_kernel<<<N_REP * BATCH * (EDIM / ETILE), 256, 0, stream>>>(a, Sg, biasg, eta, out);
}